// Round 1
// baseline (48.875 us; speedup 1.0000x reference)
//
#include <hip/hip_runtime.h>

// EdgeConv2d: B=4, C=64, N=8192, K=16, C_OUT=64
// out[b,o,n] = relu( max_k ( y1[b, i1(b,n,k), o] + y2[b, i0(b,n,k), o] ) + bias[o] )
// where y1 = (W[:, :C] - W[:, C:]) @ x[b],  y2 = W[:, C:] @ x[b]
// y stored interleaved: y[b][n][0..63] = y1, y[b][n][64..127] = y2  (channel-contiguous rows)

#define BB   4
#define CCH  64
#define NN   8192
#define KK   16

// ---------------------------------------------------------------------------
// Kernel 1: y[b, n, c] = sum_k wT[k][c] * x[b, k, n]   (c = 0..127)
// Block: 256 threads, tile = 64 n, all 128 output channels.
// ---------------------------------------------------------------------------
__global__ __launch_bounds__(256) void gemm_kernel(const float* __restrict__ x,
                                                   const float* __restrict__ W,
                                                   float* __restrict__ y) {
    __shared__ float wT[64 * 132];   // [k][c], row pad 132 (528B, 16B-aligned)
    __shared__ float xs[64 * 64];    // [k][n]

    const int t   = threadIdx.x;
    const int blk = blockIdx.x;               // 512 blocks
    // batch->XCD swizzle: batch b lives on XCDs {2b, 2b+1}
    const int xcd  = blk & 7;
    const int b    = xcd >> 1;
    const int tile = ((blk >> 3) << 1) | (xcd & 1);   // 0..127
    const int n0   = tile * 64;

    // Build wT[k][c] in LDS. Wave-uniform branch (c uniform per wave),
    // coalesced 256B reads of W rows.
    {
        const int cbase = t >> 6;   // uniform per wave
        const int k     = t & 63;   // lane
        #pragma unroll
        for (int i = 0; i < 32; ++i) {
            const int c = cbase + (i << 2);
            float v;
            if (c < CCH) v = W[c * 128 + k] - W[c * 128 + 64 + k];
            else         v = W[(c - CCH) * 128 + 64 + k];
            wT[k * 132 + c] = v;
        }
    }
    // Load x tile [64 k][64 n], coalesced.
    {
        const float* xb = x + (size_t)b * CCH * NN + n0;
        #pragma unroll
        for (int i = 0; i < 16; ++i) {
            const int e = t + (i << 8);
            const int k = e >> 6, n = e & 63;
            xs[k * 64 + n] = xb[(size_t)k * NN + n];
        }
    }
    __syncthreads();

    const int c_grp = t >> 3;   // 0..31 -> c = 4*c_grp
    const int n_grp = t & 7;    // 0..7  -> n = 8*n_grp

    float acc[4][8];
    #pragma unroll
    for (int i = 0; i < 4; ++i)
        #pragma unroll
        for (int j = 0; j < 8; ++j) acc[i][j] = 0.f;

    #pragma unroll 8
    for (int k = 0; k < 64; ++k) {
        const float4 wv  = *(const float4*)&wT[k * 132 + 4 * c_grp];
        const float4 xv0 = *(const float4*)&xs[k * 64 + 8 * n_grp];
        const float4 xv1 = *(const float4*)&xs[k * 64 + 8 * n_grp + 4];
        const float wa[4] = {wv.x, wv.y, wv.z, wv.w};
        const float xa[8] = {xv0.x, xv0.y, xv0.z, xv0.w, xv1.x, xv1.y, xv1.z, xv1.w};
        #pragma unroll
        for (int i = 0; i < 4; ++i)
            #pragma unroll
            for (int j = 0; j < 8; ++j)
                acc[i][j] += wa[i] * xa[j];
    }

    // Store: y[(b*N + n)*128 + c], float4 over c; wave writes 128B-contiguous
    // segments per row.
    float* yb = y + ((size_t)b * NN + n0) * 128;
    #pragma unroll
    for (int j = 0; j < 8; ++j) {
        float4 v;
        v.x = acc[0][j]; v.y = acc[1][j]; v.z = acc[2][j]; v.w = acc[3][j];
        *(float4*)&yb[(size_t)(8 * n_grp + j) * 128 + 4 * c_grp] = v;
    }
}

// ---------------------------------------------------------------------------
// Kernel 2: gather + add + max over K, bias + relu, LDS-transposed store.
// Block: 256 threads (4 waves), tile = 32 n; wave handles 8 n, lane = channel.
// ---------------------------------------------------------------------------
__global__ __launch_bounds__(256) void gather_kernel(const float* __restrict__ y,
                                                     const int* __restrict__ edge,
                                                     const float* __restrict__ bias,
                                                     float* __restrict__ out) {
    __shared__ float so[32 * 69];   // [n_local][c], row pad 69 (bank-spread)

    const int t    = threadIdx.x;
    const int lane = t & 63;
    const int w    = t >> 6;        // wave 0..3
    const int blk  = blockIdx.x;    // 1024 blocks
    const int xcd  = blk & 7;
    const int b    = xcd >> 1;
    const int tile = ((blk >> 3) << 1) | (xcd & 1);   // 0..255
    const int n0   = tile * 32;

    const float bv = bias[lane];
    const float* yb = y + (size_t)b * NN * 128;
    const int* e0base = edge + (size_t)b * NN * KK;          // edge_index[0][b]  (neighbors j)
    const int* e1base = edge + (size_t)(BB + b) * NN * KK;   // edge_index[1][b]  (centers i)

    for (int ni = 0; ni < 8; ++ni) {
        const int n = n0 + w * 8 + ni;                        // wave-uniform
        const int4* e0 = (const int4*)(e0base + (size_t)n * KK);
        const int4* e1 = (const int4*)(e1base + (size_t)n * KK);
        float acc = -3.4e38f;
        #pragma unroll
        for (int q = 0; q < 4; ++q) {
            const int4 i0v = e0[q];
            const int4 i1v = e1[q];
            {
                const float a = yb[(size_t)i1v.x * 128 + lane];
                const float c = yb[(size_t)i0v.x * 128 + 64 + lane];
                acc = fmaxf(acc, a + c);
            }
            {
                const float a = yb[(size_t)i1v.y * 128 + lane];
                const float c = yb[(size_t)i0v.y * 128 + 64 + lane];
                acc = fmaxf(acc, a + c);
            }
            {
                const float a = yb[(size_t)i1v.z * 128 + lane];
                const float c = yb[(size_t)i0v.z * 128 + 64 + lane];
                acc = fmaxf(acc, a + c);
            }
            {
                const float a = yb[(size_t)i1v.w * 128 + lane];
                const float c = yb[(size_t)i0v.w * 128 + 64 + lane];
                acc = fmaxf(acc, a + c);
            }
        }
        so[(w * 8 + ni) * 69 + lane] = fmaxf(acc + bv, 0.f);
    }
    __syncthreads();

    // Transposed, coalesced store: out[b, c, n0 + 4q + r] = so[4q + r][c]
    float* ob = out + (size_t)b * CCH * NN + n0;
    #pragma unroll
    for (int i = 0; i < 2; ++i) {
        const int idx = t + (i << 8);    // 0..511
        const int c = idx >> 3;          // 0..63
        const int q = idx & 7;           // 0..7  -> n offset 4q
        float4 v;
        v.x = so[(4 * q + 0) * 69 + c];
        v.y = so[(4 * q + 1) * 69 + c];
        v.z = so[(4 * q + 2) * 69 + c];
        v.w = so[(4 * q + 3) * 69 + c];
        *(float4*)&ob[(size_t)c * NN + 4 * q] = v;
    }
}

extern "C" void kernel_launch(void* const* d_in, const int* in_sizes, int n_in,
                              void* d_out, int out_size, void* d_ws, size_t ws_size,
                              hipStream_t stream) {
    (void)in_sizes; (void)n_in; (void)out_size; (void)ws_size;
    const float* x    = (const float*)d_in[0];
    const int*   edge = (const int*)d_in[1];
    const float* W    = (const float*)d_in[2];
    const float* bias = (const float*)d_in[3];
    float*       out  = (float*)d_out;
    float*       y    = (float*)d_ws;    // [B][N][128] fp32 = 16 MB

    gemm_kernel<<<dim3(512), dim3(256), 0, stream>>>(x, W, y);
    gather_kernel<<<dim3(1024), dim3(256), 0, stream>>>(y, edge, bias, out);
}

// Round 2
// 45.984 us; speedup vs baseline: 1.0629x; 1.0629x over previous
//
#include <hip/hip_runtime.h>

// EdgeConv2d: B=4, C=64, N=8192, K=16, C_OUT=64
// out[b,o,n] = relu( max_k ( y1[b, i1(b,n,k), o] + y2[b, i0(b,n,k), o] ) + bias[o] )
// y1 = (W[:,:C] - W[:,C:]) @ x[b],  y2 = W[:,C:] @ x[b]
// y layout: y[b][p][n][c2], p = channel-half (0: ch 0-31, 1: ch 32-63),
//           c2 in [0,64): c2<32 -> y1[32p+c2], c2>=32 -> y2[32p+(c2-32)]
// Gather partition: XCD x owns (batch = x>>1, phase = x&1) -> 2 MB slab per XCD L2.

#define BB   4
#define CCH  64
#define NN   8192
#define KK   16

// ---------------------------------------------------------------------------
// Kernel 1: y GEMM. Block: 256 threads, tile = 64 n, all 128 stacked channels.
// ---------------------------------------------------------------------------
__global__ __launch_bounds__(256) void gemm_kernel(const float* __restrict__ x,
                                                   const float* __restrict__ W,
                                                   float* __restrict__ y) {
    __shared__ float wT[64 * 132];   // [k][s] stacked channels, row pad 132
    __shared__ float xs[64 * 64];    // [k][n]

    const int t   = threadIdx.x;
    const int blk = blockIdx.x;               // 512 blocks
    const int xcd  = blk & 7;
    const int b    = xcd >> 1;
    const int tile = ((blk >> 3) << 1) | (xcd & 1);   // 0..127
    const int n0   = tile * 64;

    // Build wT[k][s] in LDS: s<64 -> W1-W2, s>=64 -> W2. Coalesced W-row reads.
    {
        const int sbase = t >> 6;   // uniform per wave
        const int k     = t & 63;   // lane
        #pragma unroll
        for (int i = 0; i < 32; ++i) {
            const int s = sbase + (i << 2);
            float v;
            if (s < CCH) v = W[s * 128 + k] - W[s * 128 + 64 + k];
            else         v = W[(s - CCH) * 128 + 64 + k];
            wT[k * 132 + s] = v;
        }
    }
    // Load x tile [64 k][64 n], coalesced.
    {
        const float* xb = x + (size_t)b * CCH * NN + n0;
        #pragma unroll
        for (int i = 0; i < 16; ++i) {
            const int e = t + (i << 8);
            const int k = e >> 6, n = e & 63;
            xs[k * 64 + n] = xb[(size_t)k * NN + n];
        }
    }
    __syncthreads();

    // Thread computes 4 s x 8 n.  c fast across lanes -> coalesced stores.
    const int c_grp = t & 31;   // s = 4*c_grp
    const int n_grp = t >> 5;   // n = 8*n_grp .. +7

    float acc[4][8];
    #pragma unroll
    for (int i = 0; i < 4; ++i)
        #pragma unroll
        for (int j = 0; j < 8; ++j) acc[i][j] = 0.f;

    #pragma unroll 8
    for (int k = 0; k < 64; ++k) {
        const float4 wv  = *(const float4*)&wT[k * 132 + 4 * c_grp];
        const float4 xv0 = *(const float4*)&xs[k * 64 + 8 * n_grp];
        const float4 xv1 = *(const float4*)&xs[k * 64 + 8 * n_grp + 4];
        const float wa[4] = {wv.x, wv.y, wv.z, wv.w};
        const float xa[8] = {xv0.x, xv0.y, xv0.z, xv0.w, xv1.x, xv1.y, xv1.z, xv1.w};
        #pragma unroll
        for (int i = 0; i < 4; ++i)
            #pragma unroll
            for (int j = 0; j < 8; ++j)
                acc[i][j] += wa[i] * xa[j];
    }

    // Store into split layout. sg..sg+3 stay within one 32-block -> one float4.
    const int sg = 4 * c_grp;
    int p, c2;
    if (sg < 64) { p = sg >> 5;        c2 = sg & 31; }
    else         { const int c = sg - 64; p = c >> 5; c2 = 32 + (c & 31); }
    float* ybp = y + (((size_t)b * 2 + p) * NN + n0) * 64 + c2;
    #pragma unroll
    for (int j = 0; j < 8; ++j) {
        float4 v;
        v.x = acc[0][j]; v.y = acc[1][j]; v.z = acc[2][j]; v.w = acc[3][j];
        *(float4*)&ybp[(size_t)(8 * n_grp + j) * 64] = v;
    }
}

// ---------------------------------------------------------------------------
// Kernel 2: gather + add + max over K, bias + relu, LDS-transposed store.
// 2048 blocks: blk&7 = XCD -> (b = x>>1, p = x&1); tile = blk>>3 -> 32 n.
// Wave handles 8 n as 4 pairs (half-wave per n, lane&31 = channel-local).
// ---------------------------------------------------------------------------
__global__ __launch_bounds__(256) void gather_kernel(const float* __restrict__ y,
                                                     const int* __restrict__ edge,
                                                     const float* __restrict__ bias,
                                                     float* __restrict__ out) {
    __shared__ float so[32 * 33];   // [n_local][c_local]

    const int t    = threadIdx.x;
    const int lane = t & 63;
    const int w    = t >> 6;        // wave 0..3
    const int blk  = blockIdx.x;    // 2048 blocks
    const int xcd  = blk & 7;
    const int b    = xcd >> 1;
    const int p    = xcd & 1;
    const int tile = blk >> 3;      // 0..255
    const int n0   = tile * 32;

    const int half = lane >> 5;     // which n of the pair
    const int cl   = lane & 31;     // channel-local 0..31
    const float bv = bias[32 * p + cl];

    const float* yb = y + ((size_t)b * 2 + p) * NN * 64;
    const int* e0base = edge + (size_t)b * NN * KK;          // neighbors j
    const int* e1base = edge + (size_t)(BB + b) * NN * KK;   // centers i

    #pragma unroll
    for (int j = 0; j < 4; ++j) {
        const int n_x = n0 + 8 * w + 2 * j + half;           // uniform per half-wave
        const int4* e0 = (const int4*)(e0base + (size_t)n_x * KK);
        const int4* e1 = (const int4*)(e1base + (size_t)n_x * KK);
        float acc = -3.4e38f;
        #pragma unroll
        for (int q = 0; q < 4; ++q) {
            const int4 i0v = e0[q];
            const int4 i1v = e1[q];
            acc = fmaxf(acc, yb[(size_t)i1v.x * 64 + cl] + yb[(size_t)i0v.x * 64 + 32 + cl]);
            acc = fmaxf(acc, yb[(size_t)i1v.y * 64 + cl] + yb[(size_t)i0v.y * 64 + 32 + cl]);
            acc = fmaxf(acc, yb[(size_t)i1v.z * 64 + cl] + yb[(size_t)i0v.z * 64 + 32 + cl]);
            acc = fmaxf(acc, yb[(size_t)i1v.w * 64 + cl] + yb[(size_t)i0v.w * 64 + 32 + cl]);
        }
        so[(8 * w + 2 * j + half) * 33 + cl] = fmaxf(acc + bv, 0.f);
    }
    __syncthreads();

    // Transposed, coalesced store: out[b][32p + c][n0 + 4q + r]
    {
        const int c = t >> 3;       // 0..31
        const int q = t & 7;        // 0..7
        float4 v;
        v.x = so[(4 * q + 0) * 33 + c];
        v.y = so[(4 * q + 1) * 33 + c];
        v.z = so[(4 * q + 2) * 33 + c];
        v.w = so[(4 * q + 3) * 33 + c];
        float* ob = out + ((size_t)b * CCH + 32 * p + c) * NN + n0;
        *(float4*)&ob[4 * q] = v;
    }
}

extern "C" void kernel_launch(void* const* d_in, const int* in_sizes, int n_in,
                              void* d_out, int out_size, void* d_ws, size_t ws_size,
                              hipStream_t stream) {
    (void)in_sizes; (void)n_in; (void)out_size; (void)ws_size;
    const float* x    = (const float*)d_in[0];
    const int*   edge = (const int*)d_in[1];
    const float* W    = (const float*)d_in[2];
    const float* bias = (const float*)d_in[3];
    float*       out  = (float*)d_out;
    float*       y    = (float*)d_ws;    // [B][2][N][64] fp32 = 16 MB

    gemm_kernel<<<dim3(512), dim3(256), 0, stream>>>(x, W, y);
    gather_kernel<<<dim3(2048), dim3(256), 0, stream>>>(y, edge, bias, out);
}